// Round 10
// baseline (493.596 us; speedup 1.0000x reference)
//
#include <hip/hip_runtime.h>
#include <cstddef>
#include <cstdint>

#define NEV   4096
#define NPAIR 32768
#define NEDGE (2*NPAIR)
#define EDIM  768
#define CDIM  256
#define MLPH  1024
#define LLEN  256
#define ACH   128   // k_attn edge chunk

typedef unsigned short u16;
typedef __attribute__((ext_vector_type(8))) short bhalf8;
typedef __attribute__((ext_vector_type(4))) float f32x4;

// async global->LDS, 16B per lane (HW: wave-uniform LDS base + lane*16)
#define GLOAD_LDS(g, l) __builtin_amdgcn_global_load_lds( \
    (const __attribute__((address_space(1))) unsigned int*)(g), \
    (__attribute__((address_space(3))) unsigned int*)(l), 16, 0, 0)

__device__ inline u16 f2bf(float f) {
  union { float f; unsigned u; } v; v.f = f;
  unsigned r = v.u + 0x7fffu + ((v.u >> 16) & 1u);
  return (u16)(r >> 16);
}
__device__ inline float bf2f(u16 h) {
  union { unsigned u; float f; } v; v.u = ((unsigned)h) << 16; return v.f;
}

// ---------------------------------------------------------------- k_prep: embed (blocks 0..4095) | cvt_w (4096..6399) | zero (6400..6415)
__global__ __launch_bounds__(256) void k_prep(
    const float* __restrict__ sent, const int* __restrict__ es,
    const int* __restrict__ st, const int* __restrict__ en,
    u16* __restrict__ Ahat, const float* __restrict__ W1,
    const float* __restrict__ piW, const float* __restrict__ projW,
    u16* __restrict__ BTe, u16* __restrict__ BTu,
    int* __restrict__ deg, int* __restrict__ pdeg, float* __restrict__ out)
{
  __shared__ float tile[32][33];
  int b = blockIdx.x;
  int tid = threadIdx.x;
  if (b < NEV) {
    int node = b;
    int s = es[node];
    int a = st[node];
    int span = en[node] - a;
    float fspan = (float)span;
    const float* base = sent + ((size_t)s * LLEN + a) * EDIM;
    if (tid < 192) {
      int d0 = tid * 4;
      float4 acc = {0.f, 0.f, 0.f, 0.f};
      for (int m = 0; m < span; ++m) {
        float4 v = *(const float4*)(base + (size_t)m * EDIM + d0);
        acc.x += v.x; acc.y += v.y; acc.z += v.z; acc.w += v.w;
      }
      float e[4] = {acc.x / fspan, acc.y / fspan, acc.z / fspan, acc.w / fspan};
      ushort4 hiv, lov;
      u16 h0 = f2bf(e[0]); lov.x = f2bf(e[0] - bf2f(h0)); hiv.x = h0;
      u16 h1 = f2bf(e[1]); lov.y = f2bf(e[1] - bf2f(h1)); hiv.y = h1;
      u16 h2 = f2bf(e[2]); lov.z = f2bf(e[2] - bf2f(h2)); hiv.z = h2;
      u16 h3 = f2bf(e[3]); lov.w = f2bf(e[3] - bf2f(h3)); hiv.w = h3;
      size_t bo = (size_t)node * (2 * EDIM);
      *(ushort4*)&Ahat[bo + d0] = hiv;
      *(ushort4*)&Ahat[bo + EDIM + d0] = lov;
    }
    return;
  }
  if (b < NEV + 2304) {
    int id = b - NEV;
    int bxx = id % 72, byy = id / 72;
    int which = (byy >= 24) ? 1 : 0;
    if (which && bxx >= 40) return;
    u16* BT = which ? BTu : BTe;
    int K = which ? CDIM : EDIM;
    int ld = K * 2;
    int bk = (which ? (byy - 24) : byy) * 32;
    int bc = bxx * 32;
    int tx = tid & 31, ty = tid >> 5;
#pragma unroll
    for (int rr = 0; rr < 4; ++rr) {
      int k = bk + ty + rr * 8;
      int c = bc + tx;
      float v;
      if (which == 0) {
        v = (c < 1024) ? W1[(size_t)k * MLPH + c]
          : (c < 2048) ? W1[(size_t)(EDIM + k) * MLPH + (c - 1024)]
          : piW[(size_t)k * CDIM + (c - 2048)];
      } else {
        v = (c < 1024) ? W1[(size_t)(2 * EDIM + k) * MLPH + c]
          : projW[(size_t)k * CDIM + (c - 1024)];
      }
      tile[ty + rr * 8][tx] = v;
    }
    __syncthreads();
#pragma unroll
    for (int rr = 0; rr < 4; ++rr) {
      int c = bc + ty + rr * 8;
      int k = bk + tx;
      float v = tile[tx][ty + rr * 8];
      u16 hi = f2bf(v);
      float lo = v - bf2f(hi);
      size_t bb = (size_t)c * ld;
      BT[bb + k] = hi;
      BT[bb + K + k] = f2bf(lo);
    }
    return;
  }
  int i = (b - NEV - 2304) * 256 + tid;
  if (i < NEV) { deg[i] = 0; pdeg[i] = 0; }
  if (i == 0) out[0] = 0.f;
}

// ---------------------------------------------------------------- fused CSR builds (edge-CSR by dst, pair-CSR by p0)
__global__ void k_countF(const int* __restrict__ pair, int* __restrict__ deg,
                         int* __restrict__ pdeg) {
  int e = blockIdx.x * 256 + threadIdx.x;
  if (e >= NEDGE) return;
  int p = (e < NPAIR) ? e : e - NPAIR;
  int dst = (e < NPAIR) ? pair[2 * p + 1] : pair[2 * p];
  atomicAdd(&deg[dst], 1);
  if (e < NPAIR) atomicAdd(&pdeg[pair[2 * e]], 1);
}

__device__ inline void scan_body(const int* __restrict__ deg, int* __restrict__ rowp,
                                 int* __restrict__ cursor, int* part) {
  int t = threadIdx.x;
  int base = t * 16;
  int sum = 0;
  for (int i = 0; i < 16; ++i) sum += deg[base + i];
  part[t] = sum;
  __syncthreads();
  for (int off = 1; off < 256; off <<= 1) {
    int v = (t >= off) ? part[t - off] : 0;
    __syncthreads();
    part[t] += v;
    __syncthreads();
  }
  int run = (t == 0) ? 0 : part[t - 1];
  for (int i = 0; i < 16; ++i) {
    rowp[base + i] = run;
    cursor[base + i] = 0;
    run += deg[base + i];
  }
  if (t == 255) rowp[NEV] = run;
}

__global__ void k_scanF(const int* __restrict__ deg, int* __restrict__ rowp,
                        int* __restrict__ cursor, const int* __restrict__ pdeg,
                        int* __restrict__ prow, int* __restrict__ pcur) {
  __shared__ int part[256];
  scan_body(deg, rowp, cursor, part);
  __syncthreads();
  scan_body(pdeg, prow, pcur, part);
}

__global__ void k_scatterF(const int* __restrict__ pair, const int* __restrict__ rowp,
                           int* __restrict__ cursor, int* __restrict__ e_src,
                           int* __restrict__ e_id, const int* __restrict__ prow,
                           int* __restrict__ pcur, int* __restrict__ pidx) {
  int e = blockIdx.x * 256 + threadIdx.x;
  if (e >= NEDGE) return;
  int p   = (e < NPAIR) ? e : e - NPAIR;
  int src = (e < NPAIR) ? pair[2 * p]     : pair[2 * p + 1];
  int dst = (e < NPAIR) ? pair[2 * p + 1] : pair[2 * p];
  int pos = rowp[dst] + atomicAdd(&cursor[dst], 1);
  e_src[pos] = src;
  e_id[pos]  = e;
  if (e < NPAIR) {
    int pp = prow[pair[2 * e]] + atomicAdd(&pcur[pair[2 * e]], 1);
    pidx[pp] = e;
  }
}

// ---------------------------------------------------------------- bf16x3 MFMA GEMM, 64x128 tile, hi/lo planes, 2-phase double-buffer
__global__ __launch_bounds__(256) void mgemm(
    const u16* __restrict__ A, const u16* __restrict__ BT, int K, int mode,
    float* __restrict__ G1, float* __restrict__ G2, u16* __restrict__ Xhat,
    const float* __restrict__ pib, const float* __restrict__ b1,
    const float* __restrict__ pb, float* __restrict__ U, float* __restrict__ V,
    float* __restrict__ h, const float* __restrict__ asi,
    const float* __restrict__ adi, const float* __restrict__ asj,
    const float* __restrict__ adj, float* __restrict__ sv)
{
  __shared__ u16 Ash[2 * 64 * 32];
  __shared__ u16 Asl[2 * 64 * 32];
  __shared__ u16 Bsh[2 * 128 * 32];
  __shared__ u16 Bsl[2 * 128 * 32];
  int tid = threadIdx.x;
  int wave = tid >> 6, lane = tid & 63;
  int bm = blockIdx.y * 64, bn = blockIdx.x * 128;
  int wm = (wave >> 1) * 32, wn = (wave & 1) * 64;

  int Kp2 = 2 * K;
  int srow = tid >> 2;
  int scol = (tid & 3) << 3;
  const u16* AgH  = A + (size_t)(bm + srow) * Kp2 + scol;
  const u16* BgH  = BT + (size_t)(bn + srow) * Kp2 + scol;
  const u16* BgH2 = BT + (size_t)(bn + 64 + srow) * Kp2 + scol;

  auto STAGE = [&](int buf, int kc) {
    u16* as = Ash + buf * 2048;
    u16* al = Asl + buf * 2048;
    u16* bs = Bsh + buf * 4096;
    u16* bl = Bsl + buf * 4096;
    GLOAD_LDS(AgH + kc,       &as[tid * 8]);
    GLOAD_LDS(AgH + K + kc,   &al[tid * 8]);
    GLOAD_LDS(BgH + kc,       &bs[tid * 8]);
    GLOAD_LDS(BgH2 + kc,      &bs[2048 + tid * 8]);
    GLOAD_LDS(BgH + K + kc,   &bl[tid * 8]);
    GLOAD_LDS(BgH2 + K + kc,  &bl[2048 + tid * 8]);
  };

  f32x4 acc[2][4];
#pragma unroll
  for (int i = 0; i < 2; ++i)
#pragma unroll
    for (int j = 0; j < 4; ++j) {
      f32x4 z = {0.f, 0.f, 0.f, 0.f};
      acc[i][j] = z;
    }

  int fr = lane & 15;
  int fq = lane >> 4;

  STAGE(0, 0);
  __syncthreads();
  int cur = 0;
  for (int kc = 0; kc < K; kc += 32) {
    if (kc + 32 < K) STAGE(cur ^ 1, kc + 32);
    const u16* as = Ash + cur * 2048;
    const u16* al = Asl + cur * 2048;
    const u16* bs = Bsh + cur * 4096;
    const u16* bl = Bsl + cur * 4096;
    bhalf8 afh[2], afl[2], bfh[4], bfl[4];
#pragma unroll
    for (int i = 0; i < 2; ++i) {
      afh[i] = *(const bhalf8*)&as[(wm + i * 16 + fr) * 32 + fq * 8];
      afl[i] = *(const bhalf8*)&al[(wm + i * 16 + fr) * 32 + fq * 8];
    }
#pragma unroll
    for (int j = 0; j < 4; ++j) {
      bfh[j] = *(const bhalf8*)&bs[(wn + j * 16 + fr) * 32 + fq * 8];
      bfl[j] = *(const bhalf8*)&bl[(wn + j * 16 + fr) * 32 + fq * 8];
    }
#pragma unroll
    for (int i = 0; i < 2; ++i)
#pragma unroll
      for (int j = 0; j < 4; ++j) {
        acc[i][j] = __builtin_amdgcn_mfma_f32_16x16x32_bf16(afh[i], bfh[j], acc[i][j], 0, 0, 0);
        acc[i][j] = __builtin_amdgcn_mfma_f32_16x16x32_bf16(afh[i], bfl[j], acc[i][j], 0, 0, 0);
        acc[i][j] = __builtin_amdgcn_mfma_f32_16x16x32_bf16(afl[i], bfh[j], acc[i][j], 0, 0, 0);
      }
    __syncthreads();
    cur ^= 1;
  }

#pragma unroll
  for (int i = 0; i < 2; ++i) {
    int mrow = bm + wm + i * 16 + fq * 4;
#pragma unroll
    for (int g = 0; g < 4; ++g) {
      int m = mrow + g;
#pragma unroll
      for (int j = 0; j < 4; ++j) {
        int c = bn + wn + j * 16 + fr;
        float vv = acc[i][j][g];
        if (mode == 0) {
          if (c < 1024) {
            G1[(size_t)m * MLPH + c] = vv;
          } else if (c < 2048) {
            G2[(size_t)m * MLPH + (c - 1024)] = vv;
          } else {
            int cc = c - 2048;
            float xv = vv + pib[cc];
            u16 hi = f2bf(xv);
            float lo = xv - bf2f(hi);
            size_t b = (size_t)m * (2 * CDIM);
            Xhat[b + cc] = hi;
            Xhat[b + CDIM + cc] = f2bf(lo);
          }
        } else {
          if (c < 1024) {
            size_t idx = (size_t)m * MLPH + c;
            U[idx] = G1[idx] + vv + b1[c];
            V[idx] = G2[idx] - vv;
          } else {
            int cc = c - 1024;
            h[(size_t)m * CDIM + cc] = vv + pb[cc];
          }
        }
      }
    }
  }

  // fused k_s: attention dots from h-region tiles (mode 1, bn >= MLPH)
  if (mode == 1 && bn >= MLPH) {
    int hbase = bn - MLPH + wn;
    int head = hbase >> 6;
#pragma unroll
    for (int i = 0; i < 2; ++i) {
#pragma unroll
      for (int g = 0; g < 4; ++g) {
        int m = bm + wm + i * 16 + fq * 4 + g;
        float p0 = 0.f, p1 = 0.f, p2 = 0.f, p3 = 0.f;
#pragma unroll
        for (int j = 0; j < 4; ++j) {
          int hc = hbase + j * 16 + fr;
          float hv = acc[i][j][g] + pb[hc];
          p0 += hv * asi[hc];
          p1 += hv * adi[hc];
          p2 += hv * asj[hc];
          p3 += hv * adj[hc];
        }
#pragma unroll
        for (int mm = 1; mm < 16; mm <<= 1) {
          p0 += __shfl_xor(p0, mm);
          p1 += __shfl_xor(p1, mm);
          p2 += __shfl_xor(p2, mm);
          p3 += __shfl_xor(p3, mm);
        }
        if (fr == 0) {
          sv[0 * NEV * 4 + m * 4 + head] = p0;
          sv[1 * NEV * 4 + m * 4 + head] = p1;
          sv[2 * NEV * 4 + m * 4 + head] = p2;
          sv[3 * NEV * 4 + m * 4 + head] = p3;
        }
      }
    }
  }
}

// ---------------------------------------------------------------- pred, p0-grouped, loop-invariant U/W2 in registers
__global__ __launch_bounds__(256) void k_pred_g(
    const float* __restrict__ U, const float* __restrict__ V,
    const int* __restrict__ pair, const int* __restrict__ prow,
    const int* __restrict__ pidx, const float* __restrict__ W2,
    const float* __restrict__ b2, const int* __restrict__ target,
    int* __restrict__ mstate, float* __restrict__ out,
    float* __restrict__ partials, float lossCoef)
{
  __shared__ float red[4];
  int n = blockIdx.x;
  int tid = threadIdx.x;
  int wv = tid >> 6, lane = tid & 63;
  const float* u = U + (size_t)n * MLPH;
  float4 ureg[4];
  float4 wreg[4][3];
#pragma unroll
  for (int i = 0; i < 4; ++i) {
    int kb = (lane << 2) + i * 256;
    ureg[i] = *(const float4*)(u + kb);
    const float4* w4 = (const float4*)(W2 + 3 * kb);
    wreg[i][0] = w4[0]; wreg[i][1] = w4[1]; wreg[i][2] = w4[2];
  }
  int beg = prow[n], end = prow[n + 1];
  float lsum = 0.f;
  for (int ip = beg + wv; ip < end; ip += 4) {
    int p = pidx[ip];
    int i1 = pair[2 * p + 1];
    const float* v = V + (size_t)i1 * MLPH;
    float a0 = 0.f, a1 = 0.f, a2 = 0.f;
#pragma unroll
    for (int i = 0; i < 4; ++i) {
      int kb = (lane << 2) + i * 256;
      float4 vv = *(const float4*)(v + kb);
      float4 uu = ureg[i];
      float h0 = fmaxf(uu.x + vv.x, 0.f);
      float h1 = fmaxf(uu.y + vv.y, 0.f);
      float h2 = fmaxf(uu.z + vv.z, 0.f);
      float h3 = fmaxf(uu.w + vv.w, 0.f);
      float4 wa = wreg[i][0], wb = wreg[i][1], wc = wreg[i][2];
      a0 += h0 * wa.x + h1 * wa.w + h2 * wb.z + h3 * wc.y;
      a1 += h0 * wa.y + h1 * wb.x + h2 * wb.w + h3 * wc.z;
      a2 += h0 * wa.z + h1 * wb.y + h2 * wc.x + h3 * wc.w;
    }
#pragma unroll
    for (int m = 32; m >= 1; m >>= 1) {
      a0 += __shfl_down(a0, m);
      a1 += __shfl_down(a1, m);
      a2 += __shfl_down(a2, m);
    }
    if (lane == 0) {
      a0 += b2[0]; a1 += b2[1]; a2 += b2[2];
      float mx = fmaxf(a0, fmaxf(a1, a2));
      float e0 = expf(a0 - mx), e1 = expf(a1 - mx), e2 = expf(a2 - mx);
      float sum = e0 + e1 + e2;
      int arg = 0; float best = e0;
      if (e1 > best) { best = e1; arg = 1; }
      if (e2 > best) { best = e2; arg = 2; }
      bool conf = (best / sum) > 0.5f;
      mstate[p] = conf ? arg : -1;
      int t = target[p];
      float predt = (t == 0) ? a0 : ((t == 1) ? a1 : a2);
      float logp = (predt - mx) - logf(sum);
      lsum += -logp * lossCoef;
      float* po = out + 1 + (size_t)p * 3;
      po[0] = a0; po[1] = a1; po[2] = a2;
    }
  }
  if (lane == 0) red[wv] = lsum;
  __syncthreads();
  if (tid == 0) partials[n] = red[0] + red[1] + red[2] + red[3];
}

// ---------------------------------------------------------------- attention aggregate: chunked LDS score precompute + online softmax
__global__ __launch_bounds__(256) void k_attn(
    const float* __restrict__ h, const float* __restrict__ sv,
    const int* __restrict__ rowp, const int* __restrict__ e_src,
    const int* __restrict__ e_id, const int* __restrict__ mstate,
    const int* __restrict__ rel, u16* __restrict__ Xhat,
    const float* __restrict__ lpart, float* __restrict__ out)
{
  __shared__ float sc[ACH * 4];
  __shared__ int   meta[ACH];
  int node = blockIdx.x;
  int t = threadIdx.x;          // dim 0..255; head = t>>6 (one head per wave)
  int head = t >> 6;
  const float* s_si = sv;
  const float* s_di = sv + NEV * 4;
  const float* s_sj = sv + 2 * NEV * 4;
  const float* s_dj = sv + 3 * NEV * 4;
  float4 sdi4 = *(const float4*)(s_di + node * 4);
  float4 sdj4 = *(const float4*)(s_dj + node * 4);
  int beg = rowp[node], end = rowp[node + 1];

  // init with self edge (intra, always unmasked)
  float sdi_h = ((const float*)&sdi4)[head];
  float aself = s_si[node * 4 + head] + sdi_h;
  aself = aself > 0.f ? aself : 0.2f * aself;
  float mxi = aself, deni = 1.f, acci = h[(size_t)node * CDIM + t];
  float mxj = -1e30f, denj = 0.f, accj = 0.f;

  for (int c0 = beg; c0 < end; c0 += ACH) {
    int cn = min(ACH, end - c0);
    __syncthreads();
    // step A: cooperative metadata + per-head masked scores
    for (int idx = t; idx < cn; idx += 256) {
      int e = c0 + idx;
      int eid = e_id[e];
      int pp = (eid < NPAIR) ? eid : eid - NPAIR;
      int st = mstate[pp];
      bool mall = (eid < NPAIR) ? (st == 1) : (st == 2);
      if (!mall) { meta[idx] = -1; continue; }
      int src = e_src[e];
      int r = rel[pp];
      float4 ssv = r ? *(const float4*)(s_sj + 4 * src)
                     : *(const float4*)(s_si + 4 * src);
      float4 sd = r ? sdj4 : sdi4;
      float a0 = ssv.x + sd.x; a0 = a0 > 0.f ? a0 : 0.2f * a0;
      float a1 = ssv.y + sd.y; a1 = a1 > 0.f ? a1 : 0.2f * a1;
      float a2 = ssv.z + sd.z; a2 = a2 > 0.f ? a2 : 0.2f * a2;
      float a3 = ssv.w + sd.w; a3 = a3 > 0.f ? a3 : 0.2f * a3;
      float4 av = {a0, a1, a2, a3};
      *(float4*)&sc[idx * 4] = av;
      meta[idx] = src | (r << 16);
    }
    __syncthreads();
    // step B: online softmax accumulate (branches wave-uniform: 1 head/wave)
    for (int idx = 0; idx < cn; ++idx) {
      int m = meta[idx];
      if (m < 0) continue;
      int src = m & 0xFFFF;
      int r = m >> 16;
      float a = sc[idx * 4 + head];
      float hval = h[(size_t)src * CDIM + t];
      if (r == 0) {
        if (a > mxi) {
          float s = __expf(mxi - a);
          deni *= s; acci *= s; mxi = a;
        }
        float ex = __expf(a - mxi);
        deni += ex; acci += ex * hval;
      } else {
        if (a > mxj) {
          float s = __expf(mxj - a);
          denj *= s; accj *= s; mxj = a;
        }
        float ex = __expf(a - mxj);
        denj += ex; accj += ex * hval;
      }
    }
  }

  float outv = 0.5f * (acci / (deni + 1e-9f)) + 0.5f * (accj / (denj + 1e-9f));
  u16 hi = f2bf(outv);
  float lo = outv - bf2f(hi);
  size_t b = (size_t)node * (2 * CDIM);
  Xhat[b + t] = hi;
  Xhat[b + CDIM + t] = f2bf(lo);

  // fused loss reduction (one block)
  if (blockIdx.x == 0) {
    __shared__ float sm[256];
    float s = 0.f;
    for (int i = t; i < NEV; i += 256) s += lpart[i];
    sm[t] = s;
    __syncthreads();
    for (int off = 128; off; off >>= 1) {
      if (t < off) sm[t] += sm[t + off];
      __syncthreads();
    }
    if (t == 0) out[0] += sm[0];
  }
}

// ---------------------------------------------------------------- launch
extern "C" void kernel_launch(void* const* d_in, const int* in_sizes, int n_in,
                              void* d_out, int out_size, void* d_ws, size_t ws_size,
                              hipStream_t stream)
{
  const float* sent      = (const float*)d_in[0];
  const float* proj_in_W = (const float*)d_in[1];
  const float* proj_in_b = (const float*)d_in[2];
  const float* proj_W    = (const float*)d_in[3];
  const float* proj_b    = (const float*)d_in[4];
  const float* asi       = (const float*)d_in[5];
  const float* adi       = (const float*)d_in[6];
  const float* asj       = (const float*)d_in[7];
  const float* adj       = (const float*)d_in[8];
  const float* W1        = (const float*)d_in[9];
  const float* b1        = (const float*)d_in[10];
  const float* W2        = (const float*)d_in[11];
  const float* b2        = (const float*)d_in[12];
  const int*   es        = (const int*)d_in[13];
  const int*   st        = (const int*)d_in[14];
  const int*   en        = (const int*)d_in[15];
  const int*   pair      = (const int*)d_in[16];
  const int*   rel       = (const int*)d_in[17];
  const int*   target    = (const int*)d_in[18];
  float* out = (float*)d_out;

  char* w = (char*)d_ws;
  auto alloc = [&](size_t bytes) -> char* {
    char* p = w;
    w += (bytes + 255) & ~(size_t)255;
    return p;
  };
  u16*   Ahat = (u16*)alloc(sizeof(u16) * (size_t)NEV * 2 * EDIM);
  u16*   BTe  = (u16*)alloc(sizeof(u16) * (size_t)2304 * 1536);
  u16*   BTu  = (u16*)alloc(sizeof(u16) * (size_t)1280 * 512);
  u16*   Xhat = (u16*)alloc(sizeof(u16) * (size_t)NEV * 2 * CDIM);
  float* G1   = (float*)alloc(sizeof(float) * (size_t)NEV * MLPH);
  float* G2   = (float*)alloc(sizeof(float) * (size_t)NEV * MLPH);
  float* U    = (float*)alloc(sizeof(float) * (size_t)NEV * MLPH);
  float* V    = (float*)alloc(sizeof(float) * (size_t)NEV * MLPH);
  float* h    = (float*)alloc(sizeof(float) * (size_t)NEV * CDIM);
  float* sv   = (float*)alloc(sizeof(float) * (size_t)NEV * 16);
  float* lpart= (float*)alloc(sizeof(float) * NEV);
  int* deg    = (int*)alloc(sizeof(int) * NEV);
  int* rowp   = (int*)alloc(sizeof(int) * (NEV + 1));
  int* cursor = (int*)alloc(sizeof(int) * NEV);
  int* e_src  = (int*)alloc(sizeof(int) * NEDGE);
  int* e_id   = (int*)alloc(sizeof(int) * NEDGE);
  int* pdeg   = (int*)alloc(sizeof(int) * NEV);
  int* prow   = (int*)alloc(sizeof(int) * (NEV + 1));
  int* pcur   = (int*)alloc(sizeof(int) * NEV);
  int* pidx   = (int*)alloc(sizeof(int) * NPAIR);
  int* mstate = (int*)alloc(sizeof(int) * NPAIR);

  k_prep<<<NEV + 2304 + 16, 256, 0, stream>>>(sent, es, st, en, Ahat,
                                              W1, proj_in_W, proj_W, BTe, BTu,
                                              deg, pdeg, out);
  k_countF<<<NEDGE / 256, 256, 0, stream>>>(pair, deg, pdeg);
  k_scanF<<<1, 256, 0, stream>>>(deg, rowp, cursor, pdeg, prow, pcur);
  k_scatterF<<<NEDGE / 256, 256, 0, stream>>>(pair, rowp, cursor, e_src, e_id,
                                              prow, pcur, pidx);

  mgemm<<<dim3(2304 / 128, NEV / 64), 256, 0, stream>>>(
      Ahat, BTe, EDIM, 0, G1, G2, Xhat, proj_in_b,
      nullptr, nullptr, nullptr, nullptr, nullptr,
      nullptr, nullptr, nullptr, nullptr, nullptr);

  for (int it = 0; it < 3; ++it) {
    mgemm<<<dim3(1280 / 128, NEV / 64), 256, 0, stream>>>(
        Xhat, BTu, CDIM, 1, G1, G2, nullptr, nullptr,
        b1, proj_b, U, V, h, asi, adi, asj, adj, sv);
    float coef = 1.0f / ((float)(it + 1) * (float)NPAIR);
    k_pred_g<<<NEV, 256, 0, stream>>>(U, V, pair, prow, pidx, W2, b2, target,
                                      mstate, out, lpart, coef);
    k_attn<<<NEV, 256, 0, stream>>>(h, sv, rowp, e_src, e_id, mstate, rel, Xhat,
                                    lpart, out);
  }
  (void)in_sizes; (void)n_in; (void)out_size; (void)ws_size;
}

// Round 11
// 489.763 us; speedup vs baseline: 1.0078x; 1.0078x over previous
//
#include <hip/hip_runtime.h>
#include <cstddef>
#include <cstdint>

#define NEV   4096
#define NPAIR 32768
#define NEDGE (2*NPAIR)
#define EDIM  768
#define CDIM  256
#define MLPH  1024
#define LLEN  256
#define ACH   128   // k_attn edge chunk

typedef unsigned short u16;
typedef __attribute__((ext_vector_type(8))) short bhalf8;
typedef __attribute__((ext_vector_type(4))) float f32x4;

// async global->LDS, 16B per lane (HW: wave-uniform LDS base + lane*16)
#define GLOAD_LDS(g, l) __builtin_amdgcn_global_load_lds( \
    (const __attribute__((address_space(1))) unsigned int*)(g), \
    (__attribute__((address_space(3))) unsigned int*)(l), 16, 0, 0)

__device__ inline u16 f2bf(float f) {
  union { float f; unsigned u; } v; v.f = f;
  unsigned r = v.u + 0x7fffu + ((v.u >> 16) & 1u);
  return (u16)(r >> 16);
}
__device__ inline float bf2f(u16 h) {
  union { unsigned u; float f; } v; v.u = ((unsigned)h) << 16; return v.f;
}

// ---------------------------------------------------------------- k_prep: embed (blocks 0..4095) | cvt_w (4096..6399) | zero (6400..6415)
__global__ __launch_bounds__(256) void k_prep(
    const float* __restrict__ sent, const int* __restrict__ es,
    const int* __restrict__ st, const int* __restrict__ en,
    u16* __restrict__ Ahat, const float* __restrict__ W1,
    const float* __restrict__ piW, const float* __restrict__ projW,
    u16* __restrict__ BTe, u16* __restrict__ BTu,
    int* __restrict__ deg, int* __restrict__ pdeg, float* __restrict__ out)
{
  __shared__ float tile[32][33];
  int b = blockIdx.x;
  int tid = threadIdx.x;
  if (b < NEV) {
    int node = b;
    int s = es[node];
    int a = st[node];
    int span = en[node] - a;
    float fspan = (float)span;
    const float* base = sent + ((size_t)s * LLEN + a) * EDIM;
    if (tid < 192) {
      int d0 = tid * 4;
      float4 acc = {0.f, 0.f, 0.f, 0.f};
      for (int m = 0; m < span; ++m) {
        float4 v = *(const float4*)(base + (size_t)m * EDIM + d0);
        acc.x += v.x; acc.y += v.y; acc.z += v.z; acc.w += v.w;
      }
      float e[4] = {acc.x / fspan, acc.y / fspan, acc.z / fspan, acc.w / fspan};
      ushort4 hiv, lov;
      u16 h0 = f2bf(e[0]); lov.x = f2bf(e[0] - bf2f(h0)); hiv.x = h0;
      u16 h1 = f2bf(e[1]); lov.y = f2bf(e[1] - bf2f(h1)); hiv.y = h1;
      u16 h2 = f2bf(e[2]); lov.z = f2bf(e[2] - bf2f(h2)); hiv.z = h2;
      u16 h3 = f2bf(e[3]); lov.w = f2bf(e[3] - bf2f(h3)); hiv.w = h3;
      size_t bo = (size_t)node * (2 * EDIM);
      *(ushort4*)&Ahat[bo + d0] = hiv;
      *(ushort4*)&Ahat[bo + EDIM + d0] = lov;
    }
    return;
  }
  if (b < NEV + 2304) {
    int id = b - NEV;
    int bxx = id % 72, byy = id / 72;
    int which = (byy >= 24) ? 1 : 0;
    if (which && bxx >= 40) return;
    u16* BT = which ? BTu : BTe;
    int K = which ? CDIM : EDIM;
    int ld = K * 2;
    int bk = (which ? (byy - 24) : byy) * 32;
    int bc = bxx * 32;
    int tx = tid & 31, ty = tid >> 5;
#pragma unroll
    for (int rr = 0; rr < 4; ++rr) {
      int k = bk + ty + rr * 8;
      int c = bc + tx;
      float v;
      if (which == 0) {
        v = (c < 1024) ? W1[(size_t)k * MLPH + c]
          : (c < 2048) ? W1[(size_t)(EDIM + k) * MLPH + (c - 1024)]
          : piW[(size_t)k * CDIM + (c - 2048)];
      } else {
        v = (c < 1024) ? W1[(size_t)(2 * EDIM + k) * MLPH + c]
          : projW[(size_t)k * CDIM + (c - 1024)];
      }
      tile[ty + rr * 8][tx] = v;
    }
    __syncthreads();
#pragma unroll
    for (int rr = 0; rr < 4; ++rr) {
      int c = bc + ty + rr * 8;
      int k = bk + tx;
      float v = tile[tx][ty + rr * 8];
      u16 hi = f2bf(v);
      float lo = v - bf2f(hi);
      size_t bb = (size_t)c * ld;
      BT[bb + k] = hi;
      BT[bb + K + k] = f2bf(lo);
    }
    return;
  }
  int i = (b - NEV - 2304) * 256 + tid;
  if (i < NEV) { deg[i] = 0; pdeg[i] = 0; }
  if (i == 0) out[0] = 0.f;
}

// ---------------------------------------------------------------- fused CSR builds (edge-CSR by dst, pair-CSR by p0)
__global__ void k_countF(const int* __restrict__ pair, int* __restrict__ deg,
                         int* __restrict__ pdeg) {
  int e = blockIdx.x * 256 + threadIdx.x;
  if (e >= NEDGE) return;
  int p = (e < NPAIR) ? e : e - NPAIR;
  int dst = (e < NPAIR) ? pair[2 * p + 1] : pair[2 * p];
  atomicAdd(&deg[dst], 1);
  if (e < NPAIR) atomicAdd(&pdeg[pair[2 * e]], 1);
}

__device__ inline void scan_body(const int* __restrict__ deg, int* __restrict__ rowp,
                                 int* __restrict__ cursor, int* part) {
  int t = threadIdx.x;
  int base = t * 16;
  int sum = 0;
  for (int i = 0; i < 16; ++i) sum += deg[base + i];
  part[t] = sum;
  __syncthreads();
  for (int off = 1; off < 256; off <<= 1) {
    int v = (t >= off) ? part[t - off] : 0;
    __syncthreads();
    part[t] += v;
    __syncthreads();
  }
  int run = (t == 0) ? 0 : part[t - 1];
  for (int i = 0; i < 16; ++i) {
    rowp[base + i] = run;
    cursor[base + i] = 0;
    run += deg[base + i];
  }
  if (t == 255) rowp[NEV] = run;
}

__global__ void k_scanF(const int* __restrict__ deg, int* __restrict__ rowp,
                        int* __restrict__ cursor, const int* __restrict__ pdeg,
                        int* __restrict__ prow, int* __restrict__ pcur) {
  __shared__ int part[256];
  scan_body(deg, rowp, cursor, part);
  __syncthreads();
  scan_body(pdeg, prow, pcur, part);
}

__global__ void k_scatterF(const int* __restrict__ pair, const int* __restrict__ rowp,
                           int* __restrict__ cursor, int* __restrict__ e_src,
                           int* __restrict__ e_id, const int* __restrict__ prow,
                           int* __restrict__ pcur, int* __restrict__ pidx) {
  int e = blockIdx.x * 256 + threadIdx.x;
  if (e >= NEDGE) return;
  int p   = (e < NPAIR) ? e : e - NPAIR;
  int src = (e < NPAIR) ? pair[2 * p]     : pair[2 * p + 1];
  int dst = (e < NPAIR) ? pair[2 * p + 1] : pair[2 * p];
  int pos = rowp[dst] + atomicAdd(&cursor[dst], 1);
  e_src[pos] = src;
  e_id[pos]  = e;
  if (e < NPAIR) {
    int pp = prow[pair[2 * e]] + atomicAdd(&pcur[pair[2 * e]], 1);
    pidx[pp] = e;
  }
}

// ---------------------------------------------------------------- bf16x3 MFMA GEMM, 64x128 tile, hi/lo planes, dbuf + T2 granule swizzle
// LDS rows are 32 bf16 (64B) = 4 granules of 16B. Linear layout -> 8-way bank
// conflict on ds_read_b128 (16 rows x same granule -> 2 bank-slots). Fix (rule
// #21, both-sides): LDS granule g of row r holds GLOBAL granule g ^ ((r>>1)&3)
// (via pre-swizzled global source; LDS dest linear), reads use g = fq^((r>>1)&3)
// -> 8 bank-slots, 2-way = free.
__global__ __launch_bounds__(256) void mgemm(
    const u16* __restrict__ A, const u16* __restrict__ BT, int K, int mode,
    float* __restrict__ G1, float* __restrict__ G2, u16* __restrict__ Xhat,
    const float* __restrict__ pib, const float* __restrict__ b1,
    const float* __restrict__ pb, float* __restrict__ U, float* __restrict__ V,
    float* __restrict__ h, const float* __restrict__ asi,
    const float* __restrict__ adi, const float* __restrict__ asj,
    const float* __restrict__ adj, float* __restrict__ sv)
{
  __shared__ u16 Ash[2 * 64 * 32];
  __shared__ u16 Asl[2 * 64 * 32];
  __shared__ u16 Bsh[2 * 128 * 32];
  __shared__ u16 Bsl[2 * 128 * 32];
  int tid = threadIdx.x;
  int wave = tid >> 6, lane = tid & 63;
  int bm = blockIdx.y * 64, bn = blockIdx.x * 128;
  int wm = (wave >> 1) * 32, wn = (wave & 1) * 64;

  int Kp2 = 2 * K;
  int srow = tid >> 2;                       // 0..63
  int gsw  = (((tid & 3) ^ ((srow >> 1) & 3)) << 3);  // swizzled source granule (elems)
  const u16* AgH  = A + (size_t)(bm + srow) * Kp2 + gsw;
  const u16* BgH  = BT + (size_t)(bn + srow) * Kp2 + gsw;
  const u16* BgH2 = BT + (size_t)(bn + 64 + srow) * Kp2 + gsw;  // (64+srow)>>1&3 == srow>>1&3

  auto STAGE = [&](int buf, int kc) {
    u16* as = Ash + buf * 2048;
    u16* al = Asl + buf * 2048;
    u16* bs = Bsh + buf * 4096;
    u16* bl = Bsl + buf * 4096;
    GLOAD_LDS(AgH + kc,       &as[tid * 8]);
    GLOAD_LDS(AgH + K + kc,   &al[tid * 8]);
    GLOAD_LDS(BgH + kc,       &bs[tid * 8]);
    GLOAD_LDS(BgH2 + kc,      &bs[2048 + tid * 8]);
    GLOAD_LDS(BgH + K + kc,   &bl[tid * 8]);
    GLOAD_LDS(BgH2 + K + kc,  &bl[2048 + tid * 8]);
  };

  f32x4 acc[2][4];
#pragma unroll
  for (int i = 0; i < 2; ++i)
#pragma unroll
    for (int j = 0; j < 4; ++j) {
      f32x4 z = {0.f, 0.f, 0.f, 0.f};
      acc[i][j] = z;
    }

  int fr = lane & 15;
  int fq = lane >> 4;

  // per-row swizzled read offsets (row*32 + (fq ^ ((row>>1)&3))*8)
  int rowA0 = wm + fr,      rowA1 = wm + 16 + fr;
  int offA0 = rowA0 * 32 + ((fq ^ ((rowA0 >> 1) & 3)) << 3);
  int offA1 = rowA1 * 32 + ((fq ^ ((rowA1 >> 1) & 3)) << 3);
  int offB[4];
#pragma unroll
  for (int j = 0; j < 4; ++j) {
    int rowB = wn + j * 16 + fr;
    offB[j] = rowB * 32 + ((fq ^ ((rowB >> 1) & 3)) << 3);
  }

  STAGE(0, 0);
  __syncthreads();
  int cur = 0;
  for (int kc = 0; kc < K; kc += 32) {
    if (kc + 32 < K) STAGE(cur ^ 1, kc + 32);
    const u16* as = Ash + cur * 2048;
    const u16* al = Asl + cur * 2048;
    const u16* bs = Bsh + cur * 4096;
    const u16* bl = Bsl + cur * 4096;
    bhalf8 afh[2], afl[2], bfh[4], bfl[4];
    afh[0] = *(const bhalf8*)&as[offA0];
    afh[1] = *(const bhalf8*)&as[offA1];
    afl[0] = *(const bhalf8*)&al[offA0];
    afl[1] = *(const bhalf8*)&al[offA1];
#pragma unroll
    for (int j = 0; j < 4; ++j) {
      bfh[j] = *(const bhalf8*)&bs[offB[j]];
      bfl[j] = *(const bhalf8*)&bl[offB[j]];
    }
#pragma unroll
    for (int i = 0; i < 2; ++i)
#pragma unroll
      for (int j = 0; j < 4; ++j) {
        acc[i][j] = __builtin_amdgcn_mfma_f32_16x16x32_bf16(afh[i], bfh[j], acc[i][j], 0, 0, 0);
        acc[i][j] = __builtin_amdgcn_mfma_f32_16x16x32_bf16(afh[i], bfl[j], acc[i][j], 0, 0, 0);
        acc[i][j] = __builtin_amdgcn_mfma_f32_16x16x32_bf16(afl[i], bfh[j], acc[i][j], 0, 0, 0);
      }
    __syncthreads();
    cur ^= 1;
  }

#pragma unroll
  for (int i = 0; i < 2; ++i) {
    int mrow = bm + wm + i * 16 + fq * 4;
#pragma unroll
    for (int g = 0; g < 4; ++g) {
      int m = mrow + g;
#pragma unroll
      for (int j = 0; j < 4; ++j) {
        int c = bn + wn + j * 16 + fr;
        float vv = acc[i][j][g];
        if (mode == 0) {
          if (c < 1024) {
            G1[(size_t)m * MLPH + c] = vv;
          } else if (c < 2048) {
            G2[(size_t)m * MLPH + (c - 1024)] = vv;
          } else {
            int cc = c - 2048;
            float xv = vv + pib[cc];
            u16 hi = f2bf(xv);
            float lo = xv - bf2f(hi);
            size_t b = (size_t)m * (2 * CDIM);
            Xhat[b + cc] = hi;
            Xhat[b + CDIM + cc] = f2bf(lo);
          }
        } else {
          if (c < 1024) {
            size_t idx = (size_t)m * MLPH + c;
            U[idx] = G1[idx] + vv + b1[c];
            V[idx] = G2[idx] - vv;
          } else {
            int cc = c - 1024;
            h[(size_t)m * CDIM + cc] = vv + pb[cc];
          }
        }
      }
    }
  }

  // fused k_s: attention dots from h-region tiles (mode 1, bn >= MLPH)
  if (mode == 1 && bn >= MLPH) {
    int hbase = bn - MLPH + wn;
    int head = hbase >> 6;
#pragma unroll
    for (int i = 0; i < 2; ++i) {
#pragma unroll
      for (int g = 0; g < 4; ++g) {
        int m = bm + wm + i * 16 + fq * 4 + g;
        float p0 = 0.f, p1 = 0.f, p2 = 0.f, p3 = 0.f;
#pragma unroll
        for (int j = 0; j < 4; ++j) {
          int hc = hbase + j * 16 + fr;
          float hv = acc[i][j][g] + pb[hc];
          p0 += hv * asi[hc];
          p1 += hv * adi[hc];
          p2 += hv * asj[hc];
          p3 += hv * adj[hc];
        }
#pragma unroll
        for (int mm = 1; mm < 16; mm <<= 1) {
          p0 += __shfl_xor(p0, mm);
          p1 += __shfl_xor(p1, mm);
          p2 += __shfl_xor(p2, mm);
          p3 += __shfl_xor(p3, mm);
        }
        if (fr == 0) {
          sv[0 * NEV * 4 + m * 4 + head] = p0;
          sv[1 * NEV * 4 + m * 4 + head] = p1;
          sv[2 * NEV * 4 + m * 4 + head] = p2;
          sv[3 * NEV * 4 + m * 4 + head] = p3;
        }
      }
    }
  }
}

// ---------------------------------------------------------------- pred, p0-grouped, loop-invariant U/W2 in registers
__global__ __launch_bounds__(256) void k_pred_g(
    const float* __restrict__ U, const float* __restrict__ V,
    const int* __restrict__ pair, const int* __restrict__ prow,
    const int* __restrict__ pidx, const float* __restrict__ W2,
    const float* __restrict__ b2, const int* __restrict__ target,
    int* __restrict__ mstate, float* __restrict__ out,
    float* __restrict__ partials, float lossCoef)
{
  __shared__ float red[4];
  int n = blockIdx.x;
  int tid = threadIdx.x;
  int wv = tid >> 6, lane = tid & 63;
  const float* u = U + (size_t)n * MLPH;
  float4 ureg[4];
  float4 wreg[4][3];
#pragma unroll
  for (int i = 0; i < 4; ++i) {
    int kb = (lane << 2) + i * 256;
    ureg[i] = *(const float4*)(u + kb);
    const float4* w4 = (const float4*)(W2 + 3 * kb);
    wreg[i][0] = w4[0]; wreg[i][1] = w4[1]; wreg[i][2] = w4[2];
  }
  int beg = prow[n], end = prow[n + 1];
  float lsum = 0.f;
  for (int ip = beg + wv; ip < end; ip += 4) {
    int p = pidx[ip];
    int i1 = pair[2 * p + 1];
    const float* v = V + (size_t)i1 * MLPH;
    float a0 = 0.f, a1 = 0.f, a2 = 0.f;
#pragma unroll
    for (int i = 0; i < 4; ++i) {
      int kb = (lane << 2) + i * 256;
      float4 vv = *(const float4*)(v + kb);
      float4 uu = ureg[i];
      float h0 = fmaxf(uu.x + vv.x, 0.f);
      float h1 = fmaxf(uu.y + vv.y, 0.f);
      float h2 = fmaxf(uu.z + vv.z, 0.f);
      float h3 = fmaxf(uu.w + vv.w, 0.f);
      float4 wa = wreg[i][0], wb = wreg[i][1], wc = wreg[i][2];
      a0 += h0 * wa.x + h1 * wa.w + h2 * wb.z + h3 * wc.y;
      a1 += h0 * wa.y + h1 * wb.x + h2 * wb.w + h3 * wc.z;
      a2 += h0 * wa.z + h1 * wb.y + h2 * wc.x + h3 * wc.w;
    }
#pragma unroll
    for (int m = 32; m >= 1; m >>= 1) {
      a0 += __shfl_down(a0, m);
      a1 += __shfl_down(a1, m);
      a2 += __shfl_down(a2, m);
    }
    if (lane == 0) {
      a0 += b2[0]; a1 += b2[1]; a2 += b2[2];
      float mx = fmaxf(a0, fmaxf(a1, a2));
      float e0 = expf(a0 - mx), e1 = expf(a1 - mx), e2 = expf(a2 - mx);
      float sum = e0 + e1 + e2;
      int arg = 0; float best = e0;
      if (e1 > best) { best = e1; arg = 1; }
      if (e2 > best) { best = e2; arg = 2; }
      bool conf = (best / sum) > 0.5f;
      mstate[p] = conf ? arg : -1;
      int t = target[p];
      float predt = (t == 0) ? a0 : ((t == 1) ? a1 : a2);
      float logp = (predt - mx) - logf(sum);
      lsum += -logp * lossCoef;
      float* po = out + 1 + (size_t)p * 3;
      po[0] = a0; po[1] = a1; po[2] = a2;
    }
  }
  if (lane == 0) red[wv] = lsum;
  __syncthreads();
  if (tid == 0) partials[n] = red[0] + red[1] + red[2] + red[3];
}

// ---------------------------------------------------------------- attention aggregate: chunked LDS score precompute + online softmax
__global__ __launch_bounds__(256) void k_attn(
    const float* __restrict__ h, const float* __restrict__ sv,
    const int* __restrict__ rowp, const int* __restrict__ e_src,
    const int* __restrict__ e_id, const int* __restrict__ mstate,
    const int* __restrict__ rel, u16* __restrict__ Xhat,
    const float* __restrict__ lpart, float* __restrict__ out)
{
  __shared__ float sc[ACH * 4];
  __shared__ int   meta[ACH];
  int node = blockIdx.x;
  int t = threadIdx.x;          // dim 0..255; head = t>>6 (one head per wave)
  int head = t >> 6;
  const float* s_si = sv;
  const float* s_di = sv + NEV * 4;
  const float* s_sj = sv + 2 * NEV * 4;
  const float* s_dj = sv + 3 * NEV * 4;
  float4 sdi4 = *(const float4*)(s_di + node * 4);
  float4 sdj4 = *(const float4*)(s_dj + node * 4);
  int beg = rowp[node], end = rowp[node + 1];

  // init with self edge (intra, always unmasked)
  float sdi_h = ((const float*)&sdi4)[head];
  float aself = s_si[node * 4 + head] + sdi_h;
  aself = aself > 0.f ? aself : 0.2f * aself;
  float mxi = aself, deni = 1.f, acci = h[(size_t)node * CDIM + t];
  float mxj = -1e30f, denj = 0.f, accj = 0.f;

  for (int c0 = beg; c0 < end; c0 += ACH) {
    int cn = min(ACH, end - c0);
    __syncthreads();
    for (int idx = t; idx < cn; idx += 256) {
      int e = c0 + idx;
      int eid = e_id[e];
      int pp = (eid < NPAIR) ? eid : eid - NPAIR;
      int st = mstate[pp];
      bool mall = (eid < NPAIR) ? (st == 1) : (st == 2);
      if (!mall) { meta[idx] = -1; continue; }
      int src = e_src[e];
      int r = rel[pp];
      float4 ssv = r ? *(const float4*)(s_sj + 4 * src)
                     : *(const float4*)(s_si + 4 * src);
      float4 sd = r ? sdj4 : sdi4;
      float a0 = ssv.x + sd.x; a0 = a0 > 0.f ? a0 : 0.2f * a0;
      float a1 = ssv.y + sd.y; a1 = a1 > 0.f ? a1 : 0.2f * a1;
      float a2 = ssv.z + sd.z; a2 = a2 > 0.f ? a2 : 0.2f * a2;
      float a3 = ssv.w + sd.w; a3 = a3 > 0.f ? a3 : 0.2f * a3;
      float4 av = {a0, a1, a2, a3};
      *(float4*)&sc[idx * 4] = av;
      meta[idx] = src | (r << 16);
    }
    __syncthreads();
    for (int idx = 0; idx < cn; ++idx) {
      int m = meta[idx];
      if (m < 0) continue;
      int src = m & 0xFFFF;
      int r = m >> 16;
      float a = sc[idx * 4 + head];
      float hval = h[(size_t)src * CDIM + t];
      if (r == 0) {
        if (a > mxi) {
          float s = __expf(mxi - a);
          deni *= s; acci *= s; mxi = a;
        }
        float ex = __expf(a - mxi);
        deni += ex; acci += ex * hval;
      } else {
        if (a > mxj) {
          float s = __expf(mxj - a);
          denj *= s; accj *= s; mxj = a;
        }
        float ex = __expf(a - mxj);
        denj += ex; accj += ex * hval;
      }
    }
  }

  float outv = 0.5f * (acci / (deni + 1e-9f)) + 0.5f * (accj / (denj + 1e-9f));
  u16 hi = f2bf(outv);
  float lo = outv - bf2f(hi);
  size_t b = (size_t)node * (2 * CDIM);
  Xhat[b + t] = hi;
  Xhat[b + CDIM + t] = f2bf(lo);

  if (blockIdx.x == 0) {
    __shared__ float sm[256];
    float s = 0.f;
    for (int i = t; i < NEV; i += 256) s += lpart[i];
    sm[t] = s;
    __syncthreads();
    for (int off = 128; off; off >>= 1) {
      if (t < off) sm[t] += sm[t + off];
      __syncthreads();
    }
    if (t == 0) out[0] += sm[0];
  }
}

// ---------------------------------------------------------------- launch
extern "C" void kernel_launch(void* const* d_in, const int* in_sizes, int n_in,
                              void* d_out, int out_size, void* d_ws, size_t ws_size,
                              hipStream_t stream)
{
  const float* sent      = (const float*)d_in[0];
  const float* proj_in_W = (const float*)d_in[1];
  const float* proj_in_b = (const float*)d_in[2];
  const float* proj_W    = (const float*)d_in[3];
  const float* proj_b    = (const float*)d_in[4];
  const float* asi       = (const float*)d_in[5];
  const float* adi       = (const float*)d_in[6];
  const float* asj       = (const float*)d_in[7];
  const float* adj       = (const float*)d_in[8];
  const float* W1        = (const float*)d_in[9];
  const float* b1        = (const float*)d_in[10];
  const float* W2        = (const float*)d_in[11];
  const float* b2        = (const float*)d_in[12];
  const int*   es        = (const int*)d_in[13];
  const int*   st        = (const int*)d_in[14];
  const int*   en        = (const int*)d_in[15];
  const int*   pair      = (const int*)d_in[16];
  const int*   rel       = (const int*)d_in[17];
  const int*   target    = (const int*)d_in[18];
  float* out = (float*)d_out;

  char* w = (char*)d_ws;
  auto alloc = [&](size_t bytes) -> char* {
    char* p = w;
    w += (bytes + 255) & ~(size_t)255;
    return p;
  };
  u16*   Ahat = (u16*)alloc(sizeof(u16) * (size_t)NEV * 2 * EDIM);
  u16*   BTe  = (u16*)alloc(sizeof(u16) * (size_t)2304 * 1536);
  u16*   BTu  = (u16*)alloc(sizeof(u16) * (size_t)1280 * 512);
  u16*   Xhat = (u16*)alloc(sizeof(u16) * (size_t)NEV * 2 * CDIM);
  float* G1   = (float*)alloc(sizeof(float) * (size_t)NEV * MLPH);
  float* G2   = (float*)alloc(sizeof(float) * (size_t)NEV * MLPH);
  float* U    = (float*)alloc(sizeof(float) * (size_t)NEV * MLPH);
  float* V    = (float*)alloc(sizeof(float) * (size_t)NEV * MLPH);
  float* h    = (float*)alloc(sizeof(float) * (size_t)NEV * CDIM);
  float* sv   = (float*)alloc(sizeof(float) * (size_t)NEV * 16);
  float* lpart= (float*)alloc(sizeof(float) * NEV);
  int* deg    = (int*)alloc(sizeof(int) * NEV);
  int* rowp   = (int*)alloc(sizeof(int) * (NEV + 1));
  int* cursor = (int*)alloc(sizeof(int) * NEV);
  int* e_src  = (int*)alloc(sizeof(int) * NEDGE);
  int* e_id   = (int*)alloc(sizeof(int) * NEDGE);
  int* pdeg   = (int*)alloc(sizeof(int) * NEV);
  int* prow   = (int*)alloc(sizeof(int) * (NEV + 1));
  int* pcur   = (int*)alloc(sizeof(int) * NEV);
  int* pidx   = (int*)alloc(sizeof(int) * NPAIR);
  int* mstate = (int*)alloc(sizeof(int) * NPAIR);

  k_prep<<<NEV + 2304 + 16, 256, 0, stream>>>(sent, es, st, en, Ahat,
                                              W1, proj_in_W, proj_W, BTe, BTu,
                                              deg, pdeg, out);
  k_countF<<<NEDGE / 256, 256, 0, stream>>>(pair, deg, pdeg);
  k_scanF<<<1, 256, 0, stream>>>(deg, rowp, cursor, pdeg, prow, pcur);
  k_scatterF<<<NEDGE / 256, 256, 0, stream>>>(pair, rowp, cursor, e_src, e_id,
                                              prow, pcur, pidx);

  mgemm<<<dim3(2304 / 128, NEV / 64), 256, 0, stream>>>(
      Ahat, BTe, EDIM, 0, G1, G2, Xhat, proj_in_b,
      nullptr, nullptr, nullptr, nullptr, nullptr,
      nullptr, nullptr, nullptr, nullptr, nullptr);

  for (int it = 0; it < 3; ++it) {
    mgemm<<<dim3(1280 / 128, NEV / 64), 256, 0, stream>>>(
        Xhat, BTu, CDIM, 1, G1, G2, nullptr, nullptr,
        b1, proj_b, U, V, h, asi, adi, asj, adj, sv);
    float coef = 1.0f / ((float)(it + 1) * (float)NPAIR);
    k_pred_g<<<NEV, 256, 0, stream>>>(U, V, pair, prow, pidx, W2, b2, target,
                                      mstate, out, lpart, coef);
    k_attn<<<NEV, 256, 0, stream>>>(h, sv, rowp, e_src, e_id, mstate, rel, Xhat,
                                    lpart, out);
  }
  (void)in_sizes; (void)n_in; (void)out_size; (void)ws_size;
}